// Round 3
// baseline (147.744 us; speedup 1.0000x reference)
//
#include <hip/hip_runtime.h>

#define IC    128
#define OC    128
#define NL    81          // degrees 0..80
#define PTOT  6561        // (L+1)^2 positions
#define NCPT  17
#define BSTR  (IC*PTOT)   // x batch stride
#define NBLK  1681        // sum over l of ceil(16*(2l+1)/64)

typedef short short8 __attribute__((ext_vector_type(8)));
typedef float f32x4  __attribute__((ext_vector_type(4)));

__device__ __forceinline__ unsigned short f2bf(float x) {
    unsigned u = __float_as_uint(x);
    return (unsigned short)((u + 0x7FFFu + ((u >> 16) & 1u)) >> 16);
}

// One block per degree l. Emit W_l in MFMA A-fragment order so the main
// kernel loads A-frags as single fully-coalesced 16B/lane reads:
//   elem offset within degree = (of*4+kk)*512 + lane*8 + j
//   where o = of*16 + (lane&15), i = kk*32 + (lane>>4)*8 + j.
// Writes are perfectly coalesced (consecutive threads -> consecutive 2B).
__global__ __launch_bounds__(256) void shconv_prep(const float* __restrict__ w,
                                                   unsigned short* __restrict__ WtF) {
    const int l = blockIdx.x;
    int s; float fr;
    if (l < 75) { s = l / 5;  fr = (float)(l - s * 5) * 0.2f; }
    else        { s = 15;     fr = (float)(l - 75) * 0.2f;    }
    unsigned short* dst = WtF + (size_t)l * (OC * IC);
    for (int e = threadIdx.x; e < OC * IC; e += 256) {
        int j  = e & 7;
        int mm = (e >> 3) & 15;
        int gg = (e >> 7) & 3;
        int kk = (e >> 9) & 3;
        int of = e >> 11;
        int o = of * 16 + mm;
        int i = kk * 32 + gg * 8 + j;
        const float* wp = w + i * (OC * NCPT) + o * NCPT + s;
        float v = (1.0f - fr) * wp[0] + fr * wp[1];
        dst[e] = f2bf(v);
    }
}

// Block = (degree l, 64-column chunk); 4 waves, each owns a 16-column group.
// No LDS, no barrier: A-fragments stream from L2 (WtF fits in one XCD L2),
// B-fragments (x) load straight from global, coalesced along p.
__global__ __launch_bounds__(256) void shconv_main(const float* __restrict__ x,
                                                   const unsigned short* __restrict__ WtF,
                                                   float* __restrict__ out) {
    const int tid = threadIdx.x;

    // blockIdx -> (l, chunk):  cum-chunks C(2m)=m(m+1), C(2m+1)=(m+1)^2
    int q = blockIdx.x;
    int t = (int)sqrtf((float)q);
    while (t * t > q) --t;
    while ((t + 1) * (t + 1) <= q) ++t;
    int l, chunk;
    if (q < t * (t + 1)) { l = 2 * t - 1; chunk = q - t * t; }
    else                 { l = 2 * t;     chunk = q - t * (t + 1); }

    const int len  = 2 * l + 1;
    const int cols = 16 * len;
    const int c0   = chunk * 64;

    const int lane = tid & 63;
    const int wave = tid >> 6;
    const int m    = lane & 15;   // MFMA col / A-row selector
    const int g    = lane >> 4;   // k-group

    int c = c0 + wave * 16 + m;
    const bool valid = (c < cols);
    int ccl = valid ? c : (cols - 1);
    int b   = (int)((unsigned)ccl / (unsigned)len);
    int pp  = ccl - b * len;
    int p   = l * l + pp;

    const float* xg = x + (size_t)b * BSTR + (size_t)(g * 8) * PTOT + p;
    const unsigned short* wf = WtF + (size_t)l * (OC * IC) + (size_t)lane * 8;

    // this lane's 32 K-values of x (coalesced along p across lanes 0-15)
    float xv[32];
    #pragma unroll
    for (int kk = 0; kk < 4; ++kk)
        #pragma unroll
        for (int j = 0; j < 8; ++j)
            xv[kk * 8 + j] = xg[(kk * 32 + j) * PTOT];

    short8 bfr[4];
    #pragma unroll
    for (int kk = 0; kk < 4; ++kk)
        #pragma unroll
        for (int j = 0; j < 8; ++j)
            bfr[kk][j] = (short)f2bf(xv[kk * 8 + j]);

    f32x4 acc[8];
    #pragma unroll
    for (int of = 0; of < 8; ++of) acc[of] = (f32x4){0.f, 0.f, 0.f, 0.f};

    #pragma unroll
    for (int kk = 0; kk < 4; ++kk) {
        #pragma unroll
        for (int of = 0; of < 8; ++of) {
            short8 af = *(const short8*)(wf + (size_t)(of * 4 + kk) * 512);
            acc[of] = __builtin_amdgcn_mfma_f32_16x16x32_bf16(af, bfr[kk], acc[of], 0, 0, 0);
        }
    }

    if (valid) {
        float* ob = out + (size_t)b * (OC * PTOT) + p;
        #pragma unroll
        for (int of = 0; of < 8; ++of)
            #pragma unroll
            for (int j = 0; j < 4; ++j)
                ob[(of * 16 + g * 4 + j) * PTOT] = acc[of][j];
    }
}

extern "C" void kernel_launch(void* const* d_in, const int* in_sizes, int n_in,
                              void* d_out, int out_size, void* d_ws, size_t ws_size,
                              hipStream_t stream) {
    const float* x = (const float*)d_in[0];
    const float* w = (const float*)d_in[1];
    unsigned short* WtF = (unsigned short*)d_ws;    // 81*128*128 bf16 = 2.65 MB
    float* out = (float*)d_out;

    shconv_prep<<<dim3(NL),   dim3(256), 0, stream>>>(w, WtF);
    shconv_main<<<dim3(NBLK), dim3(256), 0, stream>>>(x, WtF, out);
}

// Round 4
// 132.599 us; speedup vs baseline: 1.1142x; 1.1142x over previous
//
#include <hip/hip_runtime.h>

#define IC    128
#define OC    128
#define NL    81          // degrees 0..80
#define PTOT  6561        // (L+1)^2 positions
#define NCPT  17
#define BSTR  (IC*PTOT)   // x batch stride
#define NBLK  1681        // sum over l of ceil(16*(2l+1)/64)

typedef short short8 __attribute__((ext_vector_type(8)));
typedef float f32x4  __attribute__((ext_vector_type(4)));

__device__ __forceinline__ unsigned short f2bf(float x) {
    unsigned u = __float_as_uint(x);
    return (unsigned short)((u + 0x7FFFu + ((u >> 16) & 1u)) >> 16);
}

// 4 blocks per degree l. Emit W_l in MFMA A-fragment order so the main
// kernel loads A-frags as single fully-coalesced 16B/lane reads:
//   elem offset within degree = (of*4+kk)*512 + lane*8 + j
//   where o = of*16 + (lane&15), i = kk*32 + (lane>>4)*8 + j.
__global__ __launch_bounds__(256) void shconv_prep(const float* __restrict__ w,
                                                   unsigned short* __restrict__ WtF) {
    const int l    = blockIdx.x >> 2;
    const int quad = blockIdx.x & 3;
    int s; float fr;
    if (l < 75) { s = l / 5;  fr = (float)(l - s * 5) * 0.2f; }
    else        { s = 15;     fr = (float)(l - 75) * 0.2f;    }
    unsigned short* dst = WtF + (size_t)l * (OC * IC);
    const int e0 = quad * 4096;
    for (int e = e0 + threadIdx.x; e < e0 + 4096; e += 256) {
        int j  = e & 7;
        int mm = (e >> 3) & 15;
        int gg = (e >> 7) & 3;
        int kk = (e >> 9) & 3;
        int of = e >> 11;
        int o = of * 16 + mm;
        int i = kk * 32 + gg * 8 + j;
        const float* wp = w + i * (OC * NCPT) + o * NCPT + s;
        float v = (1.0f - fr) * wp[0] + fr * wp[1];
        dst[e] = f2bf(v);
    }
}

// Block = (degree l, 64-column chunk); 4 waves, each owns a 16-column group.
// __launch_bounds__(256,4) caps VGPR at 128 so ALL 32 x-loads per lane can
// be in flight; sched_barrier(0) pins them before any convert/use.
__global__ __launch_bounds__(256, 4) void shconv_main(const float* __restrict__ x,
                                                      const unsigned short* __restrict__ WtF,
                                                      float* __restrict__ out) {
    const int tid = threadIdx.x;

    // blockIdx -> (l, chunk):  cum-chunks C(2m)=m(m+1), C(2m+1)=(m+1)^2
    int q = blockIdx.x;
    int t = (int)sqrtf((float)q);
    while (t * t > q) --t;
    while ((t + 1) * (t + 1) <= q) ++t;
    int l, chunk;
    if (q < t * (t + 1)) { l = 2 * t - 1; chunk = q - t * t; }
    else                 { l = 2 * t;     chunk = q - t * (t + 1); }

    const int len  = 2 * l + 1;
    const int cols = 16 * len;
    const int c0   = chunk * 64;

    const int lane = tid & 63;
    const int wave = tid >> 6;
    const int m    = lane & 15;   // MFMA col / A-row selector
    const int g    = lane >> 4;   // k-group

    int c = c0 + wave * 16 + m;
    const bool valid = (c < cols);
    int ccl = valid ? c : (cols - 1);
    int b   = (int)((unsigned)ccl / (unsigned)len);
    int pp  = ccl - b * len;
    int p   = l * l + pp;

    const float* xg = x + (size_t)b * BSTR + (size_t)(g * 8) * PTOT + p;
    const unsigned short* wf = WtF + (size_t)l * (OC * IC) + (size_t)lane * 8;

    // ---- issue ALL 32 x-loads, pinned before any use ----
    float xv[32];
    #pragma unroll
    for (int kk = 0; kk < 4; ++kk)
        #pragma unroll
        for (int j = 0; j < 8; ++j)
            xv[kk * 8 + j] = xg[(kk * 32 + j) * PTOT];
    __builtin_amdgcn_sched_barrier(0);

    short8 bfr[4];
    #pragma unroll
    for (int kk = 0; kk < 4; ++kk)
        #pragma unroll
        for (int j = 0; j < 8; ++j)
            bfr[kk][j] = (short)f2bf(xv[kk * 8 + j]);

    f32x4 acc[8];
    #pragma unroll
    for (int of = 0; of < 8; ++of) acc[of] = (f32x4){0.f, 0.f, 0.f, 0.f};

    // A-frags from L2: batch 8 loads per kk so they pipeline, then 8 MFMAs
    #pragma unroll
    for (int kk = 0; kk < 4; ++kk) {
        short8 af[8];
        #pragma unroll
        for (int of = 0; of < 8; ++of)
            af[of] = *(const short8*)(wf + (size_t)(of * 4 + kk) * 512);
        #pragma unroll
        for (int of = 0; of < 8; ++of)
            acc[of] = __builtin_amdgcn_mfma_f32_16x16x32_bf16(af[of], bfr[kk], acc[of], 0, 0, 0);
    }

    if (valid) {
        float* ob = out + (size_t)b * (OC * PTOT) + p;
        #pragma unroll
        for (int of = 0; of < 8; ++of)
            #pragma unroll
            for (int j = 0; j < 4; ++j)
                ob[(of * 16 + g * 4 + j) * PTOT] = acc[of][j];
    }
}

extern "C" void kernel_launch(void* const* d_in, const int* in_sizes, int n_in,
                              void* d_out, int out_size, void* d_ws, size_t ws_size,
                              hipStream_t stream) {
    const float* x = (const float*)d_in[0];
    const float* w = (const float*)d_in[1];
    unsigned short* WtF = (unsigned short*)d_ws;    // 81*128*128 bf16 = 2.65 MB
    float* out = (float*)d_out;

    shconv_prep<<<dim3(NL * 4), dim3(256), 0, stream>>>(w, WtF);
    shconv_main<<<dim3(NBLK),   dim3(256), 0, stream>>>(x, WtF, out);
}